// Round 8
// baseline (329.610 us; speedup 1.0000x reference)
//
#include <hip/hip_runtime.h>

typedef unsigned short u16;
typedef __attribute__((ext_vector_type(8))) short bf16x8;   // 8 bf16 (4 VGPRs)
typedef __attribute__((ext_vector_type(4))) float f32x4;    // 4 f32 (clang vec)

#define NS 512   // subsequences per channel
#define NL 256   // d_model
#define NBD 64   // B*D channels
#define OUT_ELEMS 8388608u          // 8*4096*256 (first output, f32)
#define BLOCK_ELEMS 134217728u      // 8*4096*4096 (second output, f32)
// block output: base OUT_ELEMS, per-batch stride 4096*4096 = 1<<24 (f32)

__device__ __forceinline__ u16 f2bf(float f) {
  union { float f; unsigned u; } v; v.f = f;
  unsigned u = v.u;
  unsigned r = (u + 0x7FFFu + ((u >> 16) & 1u)) >> 16;   // RNE
  return (u16)r;
}

__device__ __forceinline__ bf16x8 pack8(float4 a, float4 b) {
  bf16x8 r;
  r[0] = (short)f2bf(a.x); r[1] = (short)f2bf(a.y);
  r[2] = (short)f2bf(a.z); r[3] = (short)f2bf(a.w);
  r[4] = (short)f2bf(b.x); r[5] = (short)f2bf(b.y);
  r[6] = (short)f2bf(b.z); r[7] = (short)f2bf(b.w);
  return r;
}

__device__ __forceinline__ bf16x8 pack8v(f32x4 a, f32x4 b) {
  bf16x8 r;
  r[0] = (short)f2bf(a[0]); r[1] = (short)f2bf(a[1]);
  r[2] = (short)f2bf(a[2]); r[3] = (short)f2bf(a[3]);
  r[4] = (short)f2bf(b[0]); r[5] = (short)f2bf(b[1]);
  r[6] = (short)f2bf(b[2]); r[7] = (short)f2bf(b[3]);
  return r;
}

// ---------------- K0: dense zero of the whole block-output region ----------------
// Pure-write microbench of d_out + structurally-optimal zero pass. attn later
// overwrites the diagonal chunks (stream-serialized, so ordering is safe).
__global__ __launch_bounds__(256) void zero_kernel(float* __restrict__ out) {
  f32x4* p = (f32x4*)(out + OUT_ELEMS);
  const unsigned n4 = BLOCK_ELEMS / 4u;              // 33,554,432 f32x4
  const f32x4 z4 = {0.f, 0.f, 0.f, 0.f};
  const unsigned stride = gridDim.x * blockDim.x;    // 524,288
  for (unsigned i = blockIdx.x * blockDim.x + threadIdx.x; i < n4; i += stride)
    __builtin_nontemporal_store(z4, p + i);
}

// ---------------- K1: QKV projection ----------------
// q -> qws[bd][s][0:256], k -> kws[bd][s][0:256], v -> vws[bd][f][s] (transposed)
__global__ __launch_bounds__(256) void qkv_kernel(
    const float* __restrict__ x, const float* __restrict__ w,
    const float* __restrict__ bias,
    u16* __restrict__ qws, u16* __restrict__ kws, u16* __restrict__ vws)
{
  __shared__ u16 wlds[64][264];   // w-tile [out-col][k], pad 8 u16 -> 2-way (free)

  const int t = threadIdx.x;
  const int wave = t >> 6, lane = t & 63;
  const int r16 = lane & 15, kg = lane >> 4;
  const int row0 = blockIdx.x * 64;
  const int srow = row0 + wave * 16 + r16;

  bf16x8 a[8];
  {
    const float* xr = x + (size_t)srow * NL;
    for (int ks = 0; ks < 8; ++ks) {
      float4 f0 = *(const float4*)(xr + ks * 32 + kg * 8);
      float4 f1 = *(const float4*)(xr + ks * 32 + kg * 8 + 4);
      a[ks] = pack8(f0, f1);
    }
  }

  const int wr = t >> 2, qq = t & 3;   // staging: 64 w-rows x 4 quarters
  for (int ct = 0; ct < 12; ++ct) {
    const int col0 = ct * 64;
    __syncthreads();
    {
      const float* src = w + (size_t)(col0 + wr) * NL + qq * 64;
      u16* dst = &wlds[wr][qq * 64];
      for (int j = 0; j < 64; j += 8) {
        float4 f0 = *(const float4*)(src + j);
        float4 f1 = *(const float4*)(src + j + 4);
        *(bf16x8*)(void*)(dst + j) = pack8(f0, f1);
      }
    }
    __syncthreads();

    for (int cf = 0; cf < 4; ++cf) {
      const int cl = cf * 16 + r16;
      f32x4 acc = {0.f, 0.f, 0.f, 0.f};
      for (int ks = 0; ks < 8; ++ks) {
        bf16x8 b = *(const bf16x8*)(void*)&wlds[cl][ks * 32 + kg * 8];
        acc = __builtin_amdgcn_mfma_f32_16x16x32_bf16(a[ks], b, acc, 0, 0, 0);
      }
      const int o = col0 + cl;
      const float bv = bias[o];
      for (int i = 0; i < 4; ++i) {
        const float val = acc[i] + bv;
        const int grow = row0 + wave * 16 + kg * 4 + i;
        const int bd = grow >> 9, s = grow & 511;
        const u16 h = f2bf(val);
        if (o < 256)      qws[((size_t)bd * NS + s) * NL + o] = h;
        else if (o < 512) kws[((size_t)bd * NS + s) * NL + (o - 256)] = h;
        else              vws[((size_t)bd * NL + (o - 512)) * NS + s] = h;
      }
    }
  }
}

// ---------------- K2: fused attention per (channel, 64-row tile) ----------------
// Writes ONLY diag chunks (67 MB) + out0 (33.5 MB). Zeros handled by zero_kernel.
__global__ __launch_bounds__(512, 2) void attn_kernel(
    const u16* __restrict__ qws, const u16* __restrict__ kws,
    const u16* __restrict__ vws, float* __restrict__ out)
{
  __shared__ float Sm[64][516];   // logits -> e -> p (pad 4 f32)
  __shared__ float rowinv[64];

  const int rt = blockIdx.x, bd = blockIdx.y;   // rt fastest: same-channel locality
  const int b = bd >> 3, d = bd & 7;
  const int t = threadIdx.x, wave = t >> 6, lane = t & 63;
  const int r16 = lane & 15, kg = lane >> 4;
  const size_t ch = (size_t)bd * NS * NL;
  const int row0 = rt * 64;                      // global first query row of tile

  // Q fragments: 4 row-frags x 8 k-steps (all 64 rows, per wave)
  bf16x8 aq[4][8];
  for (int rf = 0; rf < 4; ++rf) {
    const u16* p = qws + ch + (size_t)(row0 + rf * 16 + r16) * NL + kg * 8;
    for (int ks = 0; ks < 8; ++ks)
      aq[rf][ks] = *(const bf16x8*)(p + ks * 32);
  }

  // QK^T / 16 -> Sm   (wave w owns key cols [w*64, w*64+64); K not duplicated)
  for (int cf = 0; cf < 4; ++cf) {
    const int s2 = wave * 64 + cf * 16 + r16;
    const u16* p = kws + ch + (size_t)s2 * NL + kg * 8;
    bf16x8 bfr[8];
    for (int ks = 0; ks < 8; ++ks)
      bfr[ks] = *(const bf16x8*)(p + ks * 32);
    for (int rf = 0; rf < 4; ++rf) {
      f32x4 acc = {0.f, 0.f, 0.f, 0.f};
      for (int ks = 0; ks < 8; ++ks)
        acc = __builtin_amdgcn_mfma_f32_16x16x32_bf16(aq[rf][ks], bfr[ks], acc, 0, 0, 0);
      for (int i = 0; i < 4; ++i)
        Sm[rf * 16 + kg * 4 + i][s2] = acc[i] * 0.0625f;
    }
  }
  __syncthreads();   // (1)

  // in-wave softmax: 8 lanes per row (row = t>>3), shuffle reduce over 8 lanes
  {
    const int row = t >> 3, c8 = t & 7;
    float m = -1e30f;
    for (int j = 0; j < 64; ++j)
      m = fmaxf(m, Sm[row][c8 + j * 8]);
    m = fmaxf(m, __shfl_xor(m, 1));
    m = fmaxf(m, __shfl_xor(m, 2));
    m = fmaxf(m, __shfl_xor(m, 4));
    float s = 0.f;
    for (int j = 0; j < 64; ++j) {
      const int c = c8 + j * 8;
      const float e = __expf(Sm[row][c] - m);
      Sm[row][c] = e;           // store e; normalize+mask next phase
      s += e;
    }
    s += __shfl_xor(s, 1);
    s += __shfl_xor(s, 2);
    s += __shfl_xor(s, 4);
    if (c8 == 0) rowinv[row] = 1.0f / s;   // denominator INCLUDES band entries
  }
  __syncthreads();   // (2)

  // normalize + band-zero (|c - s1g|<=1): write p to Sm AND stream diag chunk
  for (int k = 0; k < 16; ++k) {
    const int slot = t + k * 512;            // 64 rows x 128 f32x4 slots
    const int row = slot >> 7, c4 = slot & 127;
    const float inv = rowinv[row];
    const int s1g = row0 + row;
    f32x4 e4 = *(const f32x4*)&Sm[row][c4 * 4];
    f32x4 p;
    for (int u = 0; u < 4; ++u) {
      const int c = c4 * 4 + u;
      const int dd = c > s1g ? c - s1g : s1g - c;
      p[u] = (dd <= 1) ? 0.f : e4[u] * inv;
    }
    *(f32x4*)&Sm[row][c4 * 4] = p;
    float* brow = out + OUT_ELEMS + ((size_t)b << 24) +
                  (size_t)(d * NS + s1g) * 4096 + d * NS;
    __builtin_nontemporal_store(p, (f32x4*)brow + c4);
  }
  __syncthreads();   // (3)

  // O = P @ V   (wave w owns feature cols [w*32, w*32+32); V not duplicated)
  f32x4 accO[4][2];
  for (int rf = 0; rf < 4; ++rf)
    for (int cf = 0; cf < 2; ++cf) accO[rf][cf] = (f32x4){0, 0, 0, 0};
  for (int ks = 0; ks < 16; ++ks) {
    bf16x8 pa[4];
    for (int rf = 0; rf < 4; ++rf) {
      const float* p = &Sm[rf * 16 + r16][ks * 32 + kg * 8];
      pa[rf] = pack8v(*(const f32x4*)p, *(const f32x4*)(p + 4));
    }
    for (int cf = 0; cf < 2; ++cf) {
      const int f = wave * 32 + cf * 16 + r16;
      bf16x8 bv = *(const bf16x8*)(vws + ((size_t)bd * NL + f) * NS + ks * 32 + kg * 8);
      for (int rf = 0; rf < 4; ++rf)
        accO[rf][cf] = __builtin_amdgcn_mfma_f32_16x16x32_bf16(pa[rf], bv, accO[rf][cf], 0, 0, 0);
    }
  }
  for (int rf = 0; rf < 4; ++rf)
    for (int cf = 0; cf < 2; ++cf) {
      const int fcol = wave * 32 + cf * 16 + r16;
      for (int i = 0; i < 4; ++i) {
        const int s1 = row0 + rf * 16 + kg * 4 + i;
        __builtin_nontemporal_store(accO[rf][cf][i],
            out + (size_t)b * (4096u * 256u) + (size_t)(d * NS + s1) * NL + fcol);
      }
    }
}

extern "C" void kernel_launch(void* const* d_in, const int* in_sizes, int n_in,
                              void* d_out, int out_size, void* d_ws, size_t ws_size,
                              hipStream_t stream) {
  const float* x    = (const float*)d_in[0];   // [8,8,512,256] f32
  const float* w    = (const float*)d_in[1];   // [768,256] f32
  const float* bias = (const float*)d_in[2];   // [768] f32
  float* out = (float*)d_out;                  // f32: out(8.39M) ++ block(134.2M)

  u16* qws = (u16*)d_ws;
  u16* kws = qws + (size_t)NBD * NS * NL;
  u16* vws = kws + (size_t)NBD * NS * NL;      // 3 x 16.78 MB bf16

  // K0 zeros the whole block region densely (also an in-graph write-BW probe);
  // K2 then overwrites the diagonal chunks (stream order guarantees WAW).
  zero_kernel<<<dim3(2048), 256, 0, stream>>>(out);
  qkv_kernel<<<dim3(512), 256, 0, stream>>>(x, w, bias, qws, kws, vws);
  attn_kernel<<<dim3(8, 64), 512, 0, stream>>>(qws, kws, vws, out);
}

// Round 9
// 294.896 us; speedup vs baseline: 1.1177x; 1.1177x over previous
//
#include <hip/hip_runtime.h>

typedef unsigned short u16;
typedef __attribute__((ext_vector_type(8))) short bf16x8;   // 8 bf16 (4 VGPRs)
typedef __attribute__((ext_vector_type(4))) float f32x4;    // 4 f32 (clang vec)

#define NS 512   // subsequences per channel
#define NL 256   // d_model
#define NBD 64   // B*D channels
#define OUT_ELEMS 8388608u          // 8*4096*256 (first output, f32)
// block output: base OUT_ELEMS, per-batch stride 4096*4096 = 1<<24 (f32)

__device__ __forceinline__ u16 f2bf(float f) {
  union { float f; unsigned u; } v; v.f = f;
  unsigned u = v.u;
  unsigned r = (u + 0x7FFFu + ((u >> 16) & 1u)) >> 16;   // RNE
  return (u16)r;
}

__device__ __forceinline__ bf16x8 pack8(float4 a, float4 b) {
  bf16x8 r;
  r[0] = (short)f2bf(a.x); r[1] = (short)f2bf(a.y);
  r[2] = (short)f2bf(a.z); r[3] = (short)f2bf(a.w);
  r[4] = (short)f2bf(b.x); r[5] = (short)f2bf(b.y);
  r[6] = (short)f2bf(b.z); r[7] = (short)f2bf(b.w);
  return r;
}

__device__ __forceinline__ bf16x8 pack8v(f32x4 a, f32x4 b) {
  bf16x8 r;
  r[0] = (short)f2bf(a[0]); r[1] = (short)f2bf(a[1]);
  r[2] = (short)f2bf(a[2]); r[3] = (short)f2bf(a[3]);
  r[4] = (short)f2bf(b[0]); r[5] = (short)f2bf(b[1]);
  r[6] = (short)f2bf(b[2]); r[7] = (short)f2bf(b[3]);
  return r;
}

// ---------------- K1: QKV projection ----------------
// q -> qws[bd][s][0:256], k -> kws[bd][s][0:256], v -> vws[bd][f][s] (transposed)
__global__ __launch_bounds__(256) void qkv_kernel(
    const float* __restrict__ x, const float* __restrict__ w,
    const float* __restrict__ bias,
    u16* __restrict__ qws, u16* __restrict__ kws, u16* __restrict__ vws)
{
  __shared__ u16 wlds[64][264];   // w-tile [out-col][k], pad 8 u16 -> 2-way (free)

  const int t = threadIdx.x;
  const int wave = t >> 6, lane = t & 63;
  const int r16 = lane & 15, kg = lane >> 4;
  const int row0 = blockIdx.x * 64;
  const int srow = row0 + wave * 16 + r16;

  bf16x8 a[8];
  {
    const float* xr = x + (size_t)srow * NL;
    for (int ks = 0; ks < 8; ++ks) {
      float4 f0 = *(const float4*)(xr + ks * 32 + kg * 8);
      float4 f1 = *(const float4*)(xr + ks * 32 + kg * 8 + 4);
      a[ks] = pack8(f0, f1);
    }
  }

  const int wr = t >> 2, qq = t & 3;   // staging: 64 w-rows x 4 quarters
  for (int ct = 0; ct < 12; ++ct) {
    const int col0 = ct * 64;
    __syncthreads();
    {
      const float* src = w + (size_t)(col0 + wr) * NL + qq * 64;
      u16* dst = &wlds[wr][qq * 64];
      for (int j = 0; j < 64; j += 8) {
        float4 f0 = *(const float4*)(src + j);
        float4 f1 = *(const float4*)(src + j + 4);
        *(bf16x8*)(void*)(dst + j) = pack8(f0, f1);
      }
    }
    __syncthreads();

    for (int cf = 0; cf < 4; ++cf) {
      const int cl = cf * 16 + r16;
      f32x4 acc = {0.f, 0.f, 0.f, 0.f};
      for (int ks = 0; ks < 8; ++ks) {
        bf16x8 b = *(const bf16x8*)(void*)&wlds[cl][ks * 32 + kg * 8];
        acc = __builtin_amdgcn_mfma_f32_16x16x32_bf16(a[ks], b, acc, 0, 0, 0);
      }
      const int o = col0 + cl;
      const float bv = bias[o];
      for (int i = 0; i < 4; ++i) {
        const float val = acc[i] + bv;
        const int grow = row0 + wave * 16 + kg * 4 + i;
        const int bd = grow >> 9, s = grow & 511;
        const u16 h = f2bf(val);
        if (o < 256)      qws[((size_t)bd * NS + s) * NL + o] = h;
        else if (o < 512) kws[((size_t)bd * NS + s) * NL + (o - 256)] = h;
        else              vws[((size_t)bd * NL + (o - 512)) * NS + s] = h;
      }
    }
  }
}

// ---------------- K2: fused attention per (channel, 64-row tile) ----------------
// R7 structure verbatim; ONLY change: all d_out stores are PLAIN (non-NT).
// A/B vs R7 isolates the nontemporal flag as the write-throughput variable.
__global__ __launch_bounds__(512, 2) void attn_kernel(
    const u16* __restrict__ qws, const u16* __restrict__ kws,
    const u16* __restrict__ vws, float* __restrict__ out)
{
  __shared__ float Sm[64][516];   // logits -> e -> p (pad 4 f32)
  __shared__ float rowinv[64];

  const int rt = blockIdx.x, bd = blockIdx.y;   // rt fastest: same-channel locality
  const int b = bd >> 3, d = bd & 7;
  const int t = threadIdx.x, wave = t >> 6, lane = t & 63;
  const int r16 = lane & 15, kg = lane >> 4;
  const size_t ch = (size_t)bd * NS * NL;
  const int row0 = rt * 64;                      // global first query row of tile

  // ---- structural zeros FIRST (off-diagonal cols of this block's 64 rows) ----
  {
    const f32x4 z4 = {0.f, 0.f, 0.f, 0.f};
    float* base = out + OUT_ELEMS + ((size_t)b << 24) +
                  (size_t)(d * NS + row0) * 4096;
    const int dlo = d << 7;   // data chunk: c4 in [d*128, d*128+128)
    for (int idx = t; idx < 64 * 1024; idx += 512) {
      const int row = idx >> 10, c4 = idx & 1023;
      if ((unsigned)(c4 - dlo) >= 128u)   // wave-uniform branch
        *((f32x4*)(base + (size_t)row * 4096) + c4) = z4;
    }
  }

  // Q fragments: 4 row-frags x 8 k-steps (all 64 rows, per wave)
  bf16x8 aq[4][8];
  for (int rf = 0; rf < 4; ++rf) {
    const u16* p = qws + ch + (size_t)(row0 + rf * 16 + r16) * NL + kg * 8;
    for (int ks = 0; ks < 8; ++ks)
      aq[rf][ks] = *(const bf16x8*)(p + ks * 32);
  }

  // QK^T / 16 -> Sm   (wave w owns key cols [w*64, w*64+64); K not duplicated)
  for (int cf = 0; cf < 4; ++cf) {
    const int s2 = wave * 64 + cf * 16 + r16;
    const u16* p = kws + ch + (size_t)s2 * NL + kg * 8;
    bf16x8 bfr[8];
    for (int ks = 0; ks < 8; ++ks)
      bfr[ks] = *(const bf16x8*)(p + ks * 32);
    for (int rf = 0; rf < 4; ++rf) {
      f32x4 acc = {0.f, 0.f, 0.f, 0.f};
      for (int ks = 0; ks < 8; ++ks)
        acc = __builtin_amdgcn_mfma_f32_16x16x32_bf16(aq[rf][ks], bfr[ks], acc, 0, 0, 0);
      for (int i = 0; i < 4; ++i)
        Sm[rf * 16 + kg * 4 + i][s2] = acc[i] * 0.0625f;
    }
  }
  __syncthreads();   // (1)

  // in-wave softmax: 8 lanes per row (row = t>>3), shuffle reduce over 8 lanes
  {
    const int row = t >> 3, c8 = t & 7;
    float m = -1e30f;
    for (int j = 0; j < 64; ++j)
      m = fmaxf(m, Sm[row][c8 + j * 8]);
    m = fmaxf(m, __shfl_xor(m, 1));
    m = fmaxf(m, __shfl_xor(m, 2));
    m = fmaxf(m, __shfl_xor(m, 4));
    float s = 0.f;
    for (int j = 0; j < 64; ++j) {
      const int c = c8 + j * 8;
      const float e = __expf(Sm[row][c] - m);
      Sm[row][c] = e;           // store e; normalize+mask next phase
      s += e;
    }
    s += __shfl_xor(s, 1);
    s += __shfl_xor(s, 2);
    s += __shfl_xor(s, 4);
    if (c8 == 0) rowinv[row] = 1.0f / s;   // denominator INCLUDES band entries
  }
  __syncthreads();   // (2)

  // normalize + band-zero (|c - s1g|<=1): write p to Sm AND stream diag chunk
  for (int k = 0; k < 16; ++k) {
    const int slot = t + k * 512;            // 64 rows x 128 f32x4 slots
    const int row = slot >> 7, c4 = slot & 127;
    const float inv = rowinv[row];
    const int s1g = row0 + row;
    f32x4 e4 = *(const f32x4*)&Sm[row][c4 * 4];
    f32x4 p;
    for (int u = 0; u < 4; ++u) {
      const int c = c4 * 4 + u;
      const int dd = c > s1g ? c - s1g : s1g - c;
      p[u] = (dd <= 1) ? 0.f : e4[u] * inv;
    }
    *(f32x4*)&Sm[row][c4 * 4] = p;
    float* brow = out + OUT_ELEMS + ((size_t)b << 24) +
                  (size_t)(d * NS + s1g) * 4096 + d * NS;
    *((f32x4*)brow + c4) = p;
  }
  __syncthreads();   // (3)

  // O = P @ V   (wave w owns feature cols [w*32, w*32+32); V not duplicated)
  f32x4 accO[4][2];
  for (int rf = 0; rf < 4; ++rf)
    for (int cf = 0; cf < 2; ++cf) accO[rf][cf] = (f32x4){0, 0, 0, 0};
  for (int ks = 0; ks < 16; ++ks) {
    bf16x8 pa[4];
    for (int rf = 0; rf < 4; ++rf) {
      const float* p = &Sm[rf * 16 + r16][ks * 32 + kg * 8];
      pa[rf] = pack8v(*(const f32x4*)p, *(const f32x4*)(p + 4));
    }
    for (int cf = 0; cf < 2; ++cf) {
      const int f = wave * 32 + cf * 16 + r16;
      bf16x8 bv = *(const bf16x8*)(vws + ((size_t)bd * NL + f) * NS + ks * 32 + kg * 8);
      for (int rf = 0; rf < 4; ++rf)
        accO[rf][cf] = __builtin_amdgcn_mfma_f32_16x16x32_bf16(pa[rf], bv, accO[rf][cf], 0, 0, 0);
    }
  }
  for (int rf = 0; rf < 4; ++rf)
    for (int cf = 0; cf < 2; ++cf) {
      const int fcol = wave * 32 + cf * 16 + r16;
      for (int i = 0; i < 4; ++i) {
        const int s1 = row0 + rf * 16 + kg * 4 + i;
        out[(size_t)b * (4096u * 256u) + (size_t)(d * NS + s1) * NL + fcol] =
            accO[rf][cf][i];
      }
    }
}

extern "C" void kernel_launch(void* const* d_in, const int* in_sizes, int n_in,
                              void* d_out, int out_size, void* d_ws, size_t ws_size,
                              hipStream_t stream) {
  const float* x    = (const float*)d_in[0];   // [8,8,512,256] f32
  const float* w    = (const float*)d_in[1];   // [768,256] f32
  const float* bias = (const float*)d_in[2];   // [768] f32
  float* out = (float*)d_out;                  // f32: out(8.39M) ++ block(134.2M)

  u16* qws = (u16*)d_ws;
  u16* kws = qws + (size_t)NBD * NS * NL;
  u16* vws = kws + (size_t)NBD * NS * NL;      // 3 x 16.78 MB bf16

  // No memset: attn_kernel writes every output byte (zeros + data) itself.
  qkv_kernel<<<dim3(512), 256, 0, stream>>>(x, w, bias, qws, kws, vws);
  attn_kernel<<<dim3(8, 64), 512, 0, stream>>>(qws, kws, vws, out);
}

// Round 10
// 266.935 us; speedup vs baseline: 1.2348x; 1.1047x over previous
//
#include <hip/hip_runtime.h>

typedef unsigned short u16;
typedef __attribute__((ext_vector_type(8))) short bf16x8;   // 8 bf16 (4 VGPRs)
typedef __attribute__((ext_vector_type(4))) float f32x4;    // 4 f32 (clang vec)

#define NS 512   // subsequences per channel
#define NL 256   // d_model
#define NBD 64   // B*D channels
#define OUT_ELEMS 8388608u          // 8*4096*256 (first output, f32)
// block output: base OUT_ELEMS, per-batch stride 4096*4096 = 1<<24 (f32)

__device__ __forceinline__ u16 f2bf(float f) {
  union { float f; unsigned u; } v; v.f = f;
  unsigned u = v.u;
  unsigned r = (u + 0x7FFFu + ((u >> 16) & 1u)) >> 16;   // RNE
  return (u16)r;
}

__device__ __forceinline__ bf16x8 pack8(float4 a, float4 b) {
  bf16x8 r;
  r[0] = (short)f2bf(a.x); r[1] = (short)f2bf(a.y);
  r[2] = (short)f2bf(a.z); r[3] = (short)f2bf(a.w);
  r[4] = (short)f2bf(b.x); r[5] = (short)f2bf(b.y);
  r[6] = (short)f2bf(b.z); r[7] = (short)f2bf(b.w);
  return r;
}

__device__ __forceinline__ bf16x8 pack8v(f32x4 a, f32x4 b) {
  bf16x8 r;
  r[0] = (short)f2bf(a[0]); r[1] = (short)f2bf(a[1]);
  r[2] = (short)f2bf(a[2]); r[3] = (short)f2bf(a[3]);
  r[4] = (short)f2bf(b[0]); r[5] = (short)f2bf(b[1]);
  r[6] = (short)f2bf(b[2]); r[7] = (short)f2bf(b[3]);
  return r;
}

// ---------------- K1: QKV projection + rt0-stripe zeros ----------------
// q -> qws[bd][s][0:256], k -> kws[bd][s][0:256], v -> vws[bd][f][s] (transposed)
// Additionally zeros the off-diagonal cols of block-output rows 0..63 of its
// channel (8 rows per block), chunked per ct-iteration so the slow d_out
// stores drain under MFMA compute (d_out write path is ~2.3 TB/s; hiding
// ~59 MB here removes ~25 us from the serial total).
__global__ __launch_bounds__(256) void qkv_kernel(
    const float* __restrict__ x, const float* __restrict__ w,
    const float* __restrict__ bias,
    u16* __restrict__ qws, u16* __restrict__ kws, u16* __restrict__ vws,
    float* __restrict__ out)
{
  __shared__ u16 wlds[64][264];   // w-tile [out-col][k], pad 8 u16 -> 2-way (free)

  const int t = threadIdx.x;
  const int g = blockIdx.x;
  const int wave = t >> 6, lane = t & 63;
  const int r16 = lane & 15, kg = lane >> 4;
  const int row0 = g * 64;
  const int srow = row0 + wave * 16 + r16;

  // zero-stripe geometry: channel bd0 = g>>3, rows [(g&7)*8, +8) of rt-tile 0
  const int bd0 = g >> 3, bz = bd0 >> 3, dz = bd0 & 7, stripe = g & 7;
  const int dlo = dz << 7;
  f32x4* zbase = (f32x4*)(out + OUT_ELEMS + ((size_t)bz << 24) +
                          (size_t)(dz * NS + stripe * 8) * 4096);
  const f32x4 z4 = {0.f, 0.f, 0.f, 0.f};

  bf16x8 a[8];
  {
    const float* xr = x + (size_t)srow * NL;
    for (int ks = 0; ks < 8; ++ks) {
      float4 f0 = *(const float4*)(xr + ks * 32 + kg * 8);
      float4 f1 = *(const float4*)(xr + ks * 32 + kg * 8 + 4);
      a[ks] = pack8(f0, f1);
    }
  }

  const int wr = t >> 2, qq = t & 3;   // staging: 64 w-rows x 4 quarters
  for (int ct = 0; ct < 12; ++ct) {
    const int col0 = ct * 64;
    __syncthreads();
    {
      const float* src = w + (size_t)(col0 + wr) * NL + qq * 64;
      u16* dst = &wlds[wr][qq * 64];
      for (int j = 0; j < 64; j += 8) {
        float4 f0 = *(const float4*)(src + j);
        float4 f1 = *(const float4*)(src + j + 4);
        *(bf16x8*)(void*)(dst + j) = pack8(f0, f1);
      }
    }
    __syncthreads();

    // issue this iteration's zero chunk BEFORE compute: drains under MFMA.
    // 8 rows x 896 slots = 7168 total; chunks of 3x256; (ct*3+k) < 28 exactly.
    for (int k = 0; k < 3; ++k) {
      const int idx = (ct * 3 + k) * 256 + t;
      if (idx < 7168) {
        const int row8 = idx / 896, c = idx - row8 * 896;
        const int c4 = c + (c >= dlo ? 128 : 0);
        __builtin_nontemporal_store(z4, zbase + row8 * 1024 + c4);
      }
    }

    for (int cf = 0; cf < 4; ++cf) {
      const int cl = cf * 16 + r16;
      f32x4 acc = {0.f, 0.f, 0.f, 0.f};
      for (int ks = 0; ks < 8; ++ks) {
        bf16x8 b = *(const bf16x8*)(void*)&wlds[cl][ks * 32 + kg * 8];
        acc = __builtin_amdgcn_mfma_f32_16x16x32_bf16(a[ks], b, acc, 0, 0, 0);
      }
      const int o = col0 + cl;
      const float bv = bias[o];
      for (int i = 0; i < 4; ++i) {
        const float val = acc[i] + bv;
        const int grow = row0 + wave * 16 + kg * 4 + i;
        const int bd = grow >> 9, s = grow & 511;
        const u16 h = f2bf(val);
        if (o < 256)      qws[((size_t)bd * NS + s) * NL + o] = h;
        else if (o < 512) kws[((size_t)bd * NS + s) * NL + (o - 256)] = h;
        else              vws[((size_t)bd * NL + (o - 512)) * NS + s] = h;
      }
    }
  }
}

// ---------------- K2: fused attention per (channel, 64-row tile) ----------------
// R7 structure (NT stores, zeros-first); rt==0 blocks skip zeros (qkv did them).
__global__ __launch_bounds__(512, 2) void attn_kernel(
    const u16* __restrict__ qws, const u16* __restrict__ kws,
    const u16* __restrict__ vws, float* __restrict__ out)
{
  __shared__ float Sm[64][516];   // logits -> e -> p (pad 4 f32)
  __shared__ float rowinv[64];

  const int rt = blockIdx.x, bd = blockIdx.y;   // rt fastest: same-channel locality
  const int b = bd >> 3, d = bd & 7;
  const int t = threadIdx.x, wave = t >> 6, lane = t & 63;
  const int r16 = lane & 15, kg = lane >> 4;
  const size_t ch = (size_t)bd * NS * NL;
  const int row0 = rt * 64;                      // global first query row of tile

  // ---- structural zeros FIRST (rt>0; rt==0 stripe is zeroed by qkv_kernel) ----
  if (rt != 0) {
    const f32x4 z4 = {0.f, 0.f, 0.f, 0.f};
    float* base = out + OUT_ELEMS + ((size_t)b << 24) +
                  (size_t)(d * NS + row0) * 4096;
    const int dlo = d << 7;   // data chunk: c4 in [d*128, d*128+128)
    for (int idx = t; idx < 64 * 1024; idx += 512) {
      const int row = idx >> 10, c4 = idx & 1023;
      if ((unsigned)(c4 - dlo) >= 128u)   // wave-uniform branch
        __builtin_nontemporal_store(z4, (f32x4*)(base + (size_t)row * 4096) + c4);
    }
  }

  // Q fragments: 4 row-frags x 8 k-steps (all 64 rows, per wave)
  bf16x8 aq[4][8];
  for (int rf = 0; rf < 4; ++rf) {
    const u16* p = qws + ch + (size_t)(row0 + rf * 16 + r16) * NL + kg * 8;
    for (int ks = 0; ks < 8; ++ks)
      aq[rf][ks] = *(const bf16x8*)(p + ks * 32);
  }

  // QK^T / 16 -> Sm   (wave w owns key cols [w*64, w*64+64); K not duplicated)
  for (int cf = 0; cf < 4; ++cf) {
    const int s2 = wave * 64 + cf * 16 + r16;
    const u16* p = kws + ch + (size_t)s2 * NL + kg * 8;
    bf16x8 bfr[8];
    for (int ks = 0; ks < 8; ++ks)
      bfr[ks] = *(const bf16x8*)(p + ks * 32);
    for (int rf = 0; rf < 4; ++rf) {
      f32x4 acc = {0.f, 0.f, 0.f, 0.f};
      for (int ks = 0; ks < 8; ++ks)
        acc = __builtin_amdgcn_mfma_f32_16x16x32_bf16(aq[rf][ks], bfr[ks], acc, 0, 0, 0);
      for (int i = 0; i < 4; ++i)
        Sm[rf * 16 + kg * 4 + i][s2] = acc[i] * 0.0625f;
    }
  }
  __syncthreads();   // (1)

  // in-wave softmax: 8 lanes per row (row = t>>3), shuffle reduce over 8 lanes
  {
    const int row = t >> 3, c8 = t & 7;
    float m = -1e30f;
    for (int j = 0; j < 64; ++j)
      m = fmaxf(m, Sm[row][c8 + j * 8]);
    m = fmaxf(m, __shfl_xor(m, 1));
    m = fmaxf(m, __shfl_xor(m, 2));
    m = fmaxf(m, __shfl_xor(m, 4));
    float s = 0.f;
    for (int j = 0; j < 64; ++j) {
      const int c = c8 + j * 8;
      const float e = __expf(Sm[row][c] - m);
      Sm[row][c] = e;           // store e; normalize+mask next phase
      s += e;
    }
    s += __shfl_xor(s, 1);
    s += __shfl_xor(s, 2);
    s += __shfl_xor(s, 4);
    if (c8 == 0) rowinv[row] = 1.0f / s;   // denominator INCLUDES band entries
  }
  __syncthreads();   // (2)

  // normalize + band-zero (|c - s1g|<=1): write p to Sm AND stream diag chunk
  for (int k = 0; k < 16; ++k) {
    const int slot = t + k * 512;            // 64 rows x 128 f32x4 slots
    const int row = slot >> 7, c4 = slot & 127;
    const float inv = rowinv[row];
    const int s1g = row0 + row;
    f32x4 e4 = *(const f32x4*)&Sm[row][c4 * 4];
    f32x4 p;
    for (int u = 0; u < 4; ++u) {
      const int c = c4 * 4 + u;
      const int dd = c > s1g ? c - s1g : s1g - c;
      p[u] = (dd <= 1) ? 0.f : e4[u] * inv;
    }
    *(f32x4*)&Sm[row][c4 * 4] = p;
    float* brow = out + OUT_ELEMS + ((size_t)b << 24) +
                  (size_t)(d * NS + s1g) * 4096 + d * NS;
    __builtin_nontemporal_store(p, (f32x4*)brow + c4);
  }
  __syncthreads();   // (3)

  // O = P @ V   (wave w owns feature cols [w*32, w*32+32); V not duplicated)
  f32x4 accO[4][2];
  for (int rf = 0; rf < 4; ++rf)
    for (int cf = 0; cf < 2; ++cf) accO[rf][cf] = (f32x4){0, 0, 0, 0};
  for (int ks = 0; ks < 16; ++ks) {
    bf16x8 pa[4];
    for (int rf = 0; rf < 4; ++rf) {
      const float* p = &Sm[rf * 16 + r16][ks * 32 + kg * 8];
      pa[rf] = pack8v(*(const f32x4*)p, *(const f32x4*)(p + 4));
    }
    for (int cf = 0; cf < 2; ++cf) {
      const int f = wave * 32 + cf * 16 + r16;
      bf16x8 bv = *(const bf16x8*)(vws + ((size_t)bd * NL + f) * NS + ks * 32 + kg * 8);
      for (int rf = 0; rf < 4; ++rf)
        accO[rf][cf] = __builtin_amdgcn_mfma_f32_16x16x32_bf16(pa[rf], bv, accO[rf][cf], 0, 0, 0);
    }
  }
  for (int rf = 0; rf < 4; ++rf)
    for (int cf = 0; cf < 2; ++cf) {
      const int fcol = wave * 32 + cf * 16 + r16;
      for (int i = 0; i < 4; ++i) {
        const int s1 = row0 + rf * 16 + kg * 4 + i;
        __builtin_nontemporal_store(accO[rf][cf][i],
            out + (size_t)b * (4096u * 256u) + (size_t)(d * NS + s1) * NL + fcol);
      }
    }
}

extern "C" void kernel_launch(void* const* d_in, const int* in_sizes, int n_in,
                              void* d_out, int out_size, void* d_ws, size_t ws_size,
                              hipStream_t stream) {
  const float* x    = (const float*)d_in[0];   // [8,8,512,256] f32
  const float* w    = (const float*)d_in[1];   // [768,256] f32
  const float* bias = (const float*)d_in[2];   // [768] f32
  float* out = (float*)d_out;                  // f32: out(8.39M) ++ block(134.2M)

  u16* qws = (u16*)d_ws;
  u16* kws = qws + (size_t)NBD * NS * NL;
  u16* vws = kws + (size_t)NBD * NS * NL;      // 3 x 16.78 MB bf16

  // No memset: qkv zeros the rt0 stripes (hidden under its MFMA); attn writes
  // the rest of the output (zeros rt>0 + diag chunks + out0).
  qkv_kernel<<<dim3(512), 256, 0, stream>>>(x, w, bias, qws, kws, vws, out);
  attn_kernel<<<dim3(8, 64), 512, 0, stream>>>(qws, kws, vws, out);
}